// Round 1
// baseline (990.648 us; speedup 1.0000x reference)
//
#include <hip/hip_runtime.h>
#include <math.h>

// Problem constants
#define B_  32
#define L_  64
#define D_  512
#define V_  50257
#define LM1 63
#define OUTROW ((size_t)LM1 * V_)   // per-batch stride in out (floats)

// ---------------------------------------------------------------------------
// Kernel A: compute h1[B, D] (GRU cell with bridged init state) into ws.
// One block per batch row b, 512 threads (one per d).
// ---------------------------------------------------------------------------
__global__ __launch_bounds__(512) void prep_kernel(
    const int*   __restrict__ ids,     // [B, L]
    const float* __restrict__ hidden,  // [B, L, D]
    const float* __restrict__ emb,     // [V, D]
    const float* __restrict__ Wb,      // [1, L] -> [L]
    const float* __restrict__ bb,      // [1]
    const float* __restrict__ W_ih,    // [3D, D]
    const float* __restrict__ b_ih,    // [3D]
    const float* __restrict__ W_hh,    // [3D, D]
    const float* __restrict__ b_hh,    // [3D]
    float*       __restrict__ h1out)   // [B, D]
{
    const int b = blockIdx.x;
    const int d = threadIdx.x;

    __shared__ __align__(16) float sx0[D_];
    __shared__ __align__(16) float sh0[D_];

    // x0 = relu(emb[input_ids[:,0]])
    const int id0 = ids[b * L_];
    float x0 = emb[(size_t)id0 * D_ + d];
    x0 = x0 > 0.f ? x0 : 0.f;

    // h0 = einsum("ld,l->d", hidden[b], Wb) + bb
    float h0 = bb[0];
    const float* hb = hidden + (size_t)b * L_ * D_ + d;
    #pragma unroll 8
    for (int l = 0; l < L_; ++l) {
        h0 += hb[(size_t)l * D_] * Wb[l];
    }

    sx0[d] = x0;
    sh0[d] = h0;
    __syncthreads();

    // Six dot products of length D (gate order r, z, n)
    float ar = b_ih[d],        az = b_ih[D_ + d],        an = b_ih[2 * D_ + d];
    float br = b_hh[d],        bz = b_hh[D_ + d],        bn = b_hh[2 * D_ + d];

    const float4* wir = (const float4*)(W_ih + (size_t)d * D_);
    const float4* wiz = (const float4*)(W_ih + (size_t)(D_ + d) * D_);
    const float4* win = (const float4*)(W_ih + (size_t)(2 * D_ + d) * D_);
    const float4* whr = (const float4*)(W_hh + (size_t)d * D_);
    const float4* whz = (const float4*)(W_hh + (size_t)(D_ + d) * D_);
    const float4* whn = (const float4*)(W_hh + (size_t)(2 * D_ + d) * D_);
    const float4* x4  = (const float4*)sx0;
    const float4* h4  = (const float4*)sh0;

    #pragma unroll 4
    for (int k = 0; k < D_ / 4; ++k) {
        const float4 xv = x4[k];
        const float4 hv = h4[k];
        float4 w;
        w = wir[k]; ar += w.x * xv.x + w.y * xv.y + w.z * xv.z + w.w * xv.w;
        w = wiz[k]; az += w.x * xv.x + w.y * xv.y + w.z * xv.z + w.w * xv.w;
        w = win[k]; an += w.x * xv.x + w.y * xv.y + w.z * xv.z + w.w * xv.w;
        w = whr[k]; br += w.x * hv.x + w.y * hv.y + w.z * hv.z + w.w * hv.w;
        w = whz[k]; bz += w.x * hv.x + w.y * hv.y + w.z * hv.z + w.w * hv.w;
        w = whn[k]; bn += w.x * hv.x + w.y * hv.y + w.z * hv.z + w.w * hv.w;
    }

    const float r = 1.f / (1.f + expf(-(ar + br)));
    const float z = 1.f / (1.f + expf(-(az + bz)));
    const float n = tanhf(an + r * bn);
    const float h0v = sh0[d];
    const float h1 = (1.f - z) * n + z * h0v;

    h1out[b * D_ + d] = h1;
}

// ---------------------------------------------------------------------------
// Kernel B: logits[b, v] = h1[b] . Wp[v] + bp[v], written to out[b][0][v].
// One thread per v, 32 fp32 accumulators; h1 reads are wave-uniform
// (expect s_load_dwordx4), Wp rows are 2KB-aligned float4 streams.
// ---------------------------------------------------------------------------
__global__ __launch_bounds__(256) void logits_kernel(
    const float* __restrict__ h1,   // [B, D]
    const float* __restrict__ Wp,   // [V, D]
    const float* __restrict__ bp,   // [V]
    float*       __restrict__ out)  // [B, L-1, V]
{
    const int v = blockIdx.x * 256 + threadIdx.x;
    if (v >= V_) return;

    float acc[B_];
    #pragma unroll
    for (int b = 0; b < B_; ++b) acc[b] = 0.f;

    const float4* wp4 = (const float4*)(Wp + (size_t)v * D_);
    const float4* h14 = (const float4*)h1;

    #pragma unroll 2
    for (int k = 0; k < D_ / 4; ++k) {
        const float4 w = wp4[k];
        #pragma unroll
        for (int b = 0; b < B_; ++b) {
            const float4 h = h14[b * (D_ / 4) + k];
            acc[b] += w.x * h.x + w.y * h.y + w.z * h.z + w.w * h.w;
        }
    }

    const float bias = bp[v];
    #pragma unroll
    for (int b = 0; b < B_; ++b) {
        out[(size_t)b * OUTROW + v] = acc[b] + bias;
    }
}

// ---------------------------------------------------------------------------
// Kernel C: broadcast out[b][0][:] to out[b][l][:] for l = 1..62.
// grid = (ceil(V/1024), 62, 32), 256 threads, 4 elems/thread, coalesced.
// ---------------------------------------------------------------------------
__global__ __launch_bounds__(256) void bcast_kernel(float* out)
{
    const int b  = blockIdx.z;
    const int l  = blockIdx.y + 1;               // 1..62
    const int v0 = blockIdx.x * 1024 + threadIdx.x;

    const float* src = out + (size_t)b * OUTROW;           // l = 0 row
    float*       dst = out + (size_t)b * OUTROW + (size_t)l * V_;

    #pragma unroll
    for (int i = 0; i < 4; ++i) {
        const int v = v0 + i * 256;
        if (v < V_) {
            __builtin_nontemporal_store(src[v], dst + v);
        }
    }
}

// ---------------------------------------------------------------------------
extern "C" void kernel_launch(void* const* d_in, const int* in_sizes, int n_in,
                              void* d_out, int out_size, void* d_ws, size_t ws_size,
                              hipStream_t stream) {
    const int*   ids    = (const int*)  d_in[0];
    const float* hidden = (const float*)d_in[1];
    const float* emb    = (const float*)d_in[2];
    const float* Wb     = (const float*)d_in[3];
    const float* bb     = (const float*)d_in[4];
    const float* W_ih   = (const float*)d_in[5];
    const float* b_ih   = (const float*)d_in[6];
    const float* W_hh   = (const float*)d_in[7];
    const float* b_hh   = (const float*)d_in[8];
    const float* Wp     = (const float*)d_in[9];
    const float* bp     = (const float*)d_in[10];

    float* out = (float*)d_out;
    float* h1  = (float*)d_ws;   // 32*512*4 = 64 KB scratch

    prep_kernel<<<B_, D_, 0, stream>>>(ids, hidden, emb, Wb, bb,
                                       W_ih, b_ih, W_hh, b_hh, h1);

    logits_kernel<<<(V_ + 255) / 256, 256, 0, stream>>>(h1, Wp, bp, out);

    bcast_kernel<<<dim3((V_ + 1023) / 1024, LM1 - 1, B_), 256, 0, stream>>>(out);
}

// Round 2
// 846.324 us; speedup vs baseline: 1.1705x; 1.1705x over previous
//
#include <hip/hip_runtime.h>
#include <math.h>

// Problem constants
#define B_  32
#define L_  64
#define D_  512
#define V_  50257
#define LM1 63
#define OUTROW ((size_t)LM1 * V_)   // per-batch stride in out (floats), ODD -> no float4 on out

// ---------------------------------------------------------------------------
// Kernel A1: x0 = relu(emb[ids[:,0]]), h0 = hidden[b] . Wb + bb   -> ws
// One block per b, 512 threads (one per d). hidden reads coalesced (256B/instr).
// ---------------------------------------------------------------------------
__global__ __launch_bounds__(512) void x0h0_kernel(
    const int*   __restrict__ ids,     // [B, L]
    const float* __restrict__ hidden,  // [B, L, D]
    const float* __restrict__ emb,     // [V, D]
    const float* __restrict__ Wb,      // [L]
    const float* __restrict__ bb,      // [1]
    float*       __restrict__ x0buf,   // [B, D]
    float*       __restrict__ h0buf)   // [B, D]
{
    const int b = blockIdx.x;
    const int d = threadIdx.x;

    const int id0 = ids[b * L_];
    float x0 = emb[(size_t)id0 * D_ + d];
    x0buf[b * D_ + d] = x0 > 0.f ? x0 : 0.f;

    float h0 = bb[0];
    const float* hb = hidden + (size_t)b * L_ * D_ + d;
    #pragma unroll 8
    for (int l = 0; l < L_; ++l) h0 += hb[(size_t)l * D_] * Wb[l];
    h0buf[b * D_ + d] = h0;
}

// ---------------------------------------------------------------------------
// Kernel A2: gx = x0 @ W_ih.T, gh = h0 @ W_hh.T  (no bias here).
// 3072 rows total (1536 per matrix); block = 64 rows of one matrix,
// 256 threads = (row_lane 0..63, k_chunk 0..3), LDS reduce. Weights read ONCE.
// ---------------------------------------------------------------------------
__global__ __launch_bounds__(256) void gates_kernel(
    const float* __restrict__ x0,    // [B, D]
    const float* __restrict__ h0,    // [B, D]
    const float* __restrict__ W_ih,  // [3D, D]
    const float* __restrict__ W_hh,  // [3D, D]
    float*       __restrict__ gx,    // [B, 3D]
    float*       __restrict__ gh)    // [B, 3D]
{
    const int blk = blockIdx.x;                 // 0..47
    const int R0  = blk * 64;                   // 0..3008
    const int m   = R0 / (3 * D_);              // 0 = ih, 1 = hh (blocks never straddle)
    const int r0  = R0 % (3 * D_);
    const float* __restrict__ W  = m ? W_hh : W_ih;
    const float* __restrict__ xh = m ? h0 : x0;
    float* __restrict__ g        = m ? gh : gx;

    const int t  = threadIdx.x;
    const int rl = t & 63;
    const int kc = __builtin_amdgcn_readfirstlane(t >> 6);   // wave-uniform

    const float4* w4  = (const float4*)(W + (size_t)(r0 + rl) * D_) + kc * 32;
    const float4* xh4 = (const float4*)xh + kc * 32;          // + b*128 per batch

    float acc[B_];
    #pragma unroll
    for (int b = 0; b < B_; ++b) acc[b] = 0.f;

    #pragma unroll 4
    for (int kk = 0; kk < 32; ++kk) {
        const float4 w = w4[kk];
        #pragma unroll
        for (int b = 0; b < B_; ++b) {
            const float4 h = xh4[(size_t)b * (D_ / 4) + kk];
            acc[b] += w.x * h.x + w.y * h.y + w.z * h.z + w.w * h.w;
        }
    }

    __shared__ float red[4][B_][64];   // 32 KB
    #pragma unroll
    for (int b = 0; b < B_; ++b) red[kc][b][rl] = acc[b];
    __syncthreads();

    // thread: r4 = 4-row group (t&15), bpair = t>>4 -> b in {2*bpair, 2*bpair+1}
    const int r4 = t & 15, bpair = t >> 4;
    #pragma unroll
    for (int i = 0; i < 2; ++i) {
        const int b = 2 * bpair + i;
        float4 s = make_float4(0.f, 0.f, 0.f, 0.f);
        #pragma unroll
        for (int c = 0; c < 4; ++c) {
            const float4 u = *(const float4*)&red[c][b][4 * r4];
            s.x += u.x; s.y += u.y; s.z += u.z; s.w += u.w;
        }
        *(float4*)(g + (size_t)b * (3 * D_) + r0 + 4 * r4) = s;
    }
}

// ---------------------------------------------------------------------------
// Kernel A3: combine gates -> h1[B, D]
// ---------------------------------------------------------------------------
__global__ __launch_bounds__(256) void combine_kernel(
    const float* __restrict__ gx,    // [B, 3D]
    const float* __restrict__ gh,    // [B, 3D]
    const float* __restrict__ b_ih,  // [3D]
    const float* __restrict__ b_hh,  // [3D]
    const float* __restrict__ h0buf, // [B, D]
    float*       __restrict__ h1)    // [B, D]
{
    const int i = blockIdx.x * 256 + threadIdx.x;   // 0..16383
    const int b = i >> 9, d = i & (D_ - 1);
    const size_t g0 = (size_t)b * (3 * D_);

    const float gxr = gx[g0 + d]            + b_ih[d];
    const float gxz = gx[g0 + D_ + d]       + b_ih[D_ + d];
    const float gxn = gx[g0 + 2 * D_ + d]   + b_ih[2 * D_ + d];
    const float ghr = gh[g0 + d]            + b_hh[d];
    const float ghz = gh[g0 + D_ + d]       + b_hh[D_ + d];
    const float ghn = gh[g0 + 2 * D_ + d]   + b_hh[2 * D_ + d];

    const float r = 1.f / (1.f + expf(-(gxr + ghr)));
    const float z = 1.f / (1.f + expf(-(gxz + ghz)));
    const float n = tanhf(gxn + r * ghn);
    h1[i] = (1.f - z) * n + z * h0buf[i];
}

// ---------------------------------------------------------------------------
// Fallback prep (round-1): one block per b, writes h1 directly. Used only if
// ws_size is too small for the split pipeline.
// ---------------------------------------------------------------------------
__global__ __launch_bounds__(512) void prep_kernel(
    const int* __restrict__ ids, const float* __restrict__ hidden,
    const float* __restrict__ emb, const float* __restrict__ Wb,
    const float* __restrict__ bb, const float* __restrict__ W_ih,
    const float* __restrict__ b_ih, const float* __restrict__ W_hh,
    const float* __restrict__ b_hh, float* __restrict__ h1out)
{
    const int b = blockIdx.x;
    const int d = threadIdx.x;
    __shared__ __align__(16) float sx0[D_];
    __shared__ __align__(16) float sh0[D_];

    const int id0 = ids[b * L_];
    float x0 = emb[(size_t)id0 * D_ + d];
    x0 = x0 > 0.f ? x0 : 0.f;
    float h0 = bb[0];
    const float* hb = hidden + (size_t)b * L_ * D_ + d;
    #pragma unroll 8
    for (int l = 0; l < L_; ++l) h0 += hb[(size_t)l * D_] * Wb[l];
    sx0[d] = x0; sh0[d] = h0;
    __syncthreads();

    float ar = b_ih[d], az = b_ih[D_ + d], an = b_ih[2 * D_ + d];
    float br = b_hh[d], bz = b_hh[D_ + d], bn = b_hh[2 * D_ + d];
    const float4* wir = (const float4*)(W_ih + (size_t)d * D_);
    const float4* wiz = (const float4*)(W_ih + (size_t)(D_ + d) * D_);
    const float4* win = (const float4*)(W_ih + (size_t)(2 * D_ + d) * D_);
    const float4* whr = (const float4*)(W_hh + (size_t)d * D_);
    const float4* whz = (const float4*)(W_hh + (size_t)(D_ + d) * D_);
    const float4* whn = (const float4*)(W_hh + (size_t)(2 * D_ + d) * D_);
    const float4* x4 = (const float4*)sx0;
    const float4* h4 = (const float4*)sh0;
    #pragma unroll 4
    for (int k = 0; k < D_ / 4; ++k) {
        const float4 xv = x4[k]; const float4 hv = h4[k]; float4 w;
        w = wir[k]; ar += w.x*xv.x + w.y*xv.y + w.z*xv.z + w.w*xv.w;
        w = wiz[k]; az += w.x*xv.x + w.y*xv.y + w.z*xv.z + w.w*xv.w;
        w = win[k]; an += w.x*xv.x + w.y*xv.y + w.z*xv.z + w.w*xv.w;
        w = whr[k]; br += w.x*hv.x + w.y*hv.y + w.z*hv.z + w.w*hv.w;
        w = whz[k]; bz += w.x*hv.x + w.y*hv.y + w.z*hv.z + w.w*hv.w;
        w = whn[k]; bn += w.x*hv.x + w.y*hv.y + w.z*hv.z + w.w*hv.w;
    }
    const float r = 1.f / (1.f + expf(-(ar + br)));
    const float z = 1.f / (1.f + expf(-(az + bz)));
    const float n = tanhf(an + r * bn);
    h1out[b * D_ + d] = (1.f - z) * n + z * sh0[d];
}

// ---------------------------------------------------------------------------
// Kernel B: fused logits + broadcast.
// Block = 64 vocab columns, 256 threads = (v_lane 0..63, k_chunk 0..3).
// Dot phase -> LDS reduce -> logits in LDS -> all 63 L-slices written with
// lane-coalesced scalar NT stores (out strides are odd; float4 would misalign).
// ---------------------------------------------------------------------------
__global__ __launch_bounds__(256) void logits_bcast_kernel(
    const float* __restrict__ h1,   // [B, D]
    const float* __restrict__ Wp,   // [V, D]
    const float* __restrict__ bp,   // [V]
    float*       __restrict__ out)  // [B, L-1, V]
{
    const int t  = threadIdx.x;
    const int v0 = blockIdx.x * 64;
    const int vl = t & 63;
    const int kc = __builtin_amdgcn_readfirstlane(t >> 6);   // wave-uniform k-chunk

    const int v    = v0 + vl;
    const int vrow = v < V_ ? v : V_ - 1;                    // clamp OOB rows (never stored)

    const float4* wp4 = (const float4*)(Wp + (size_t)vrow * D_) + kc * 32;
    const float4* h4  = (const float4*)h1 + kc * 32;         // uniform -> s_load path

    float acc[B_];
    #pragma unroll
    for (int b = 0; b < B_; ++b) acc[b] = 0.f;

    #pragma unroll 4
    for (int kk = 0; kk < 32; ++kk) {
        const float4 w = wp4[kk];
        #pragma unroll
        for (int b = 0; b < B_; ++b) {
            const float4 h = h4[(size_t)b * (D_ / 4) + kk];
            acc[b] += w.x * h.x + w.y * h.y + w.z * h.z + w.w * h.w;
        }
    }

    __shared__ float red[4][B_][64];          // 32 KB, reused for logits after reduce
    float* lg = (float*)red;                  // logits_lds[b*64 + vl], 8 KB

    #pragma unroll
    for (int b = 0; b < B_; ++b) red[kc][b][vl] = acc[b];
    __syncthreads();

    // Reduce: thread (r4 = t&15 -> 4 v's, bpair = t>>4 -> 2 b's); keep in regs.
    const int r4 = t & 15, bpair = t >> 4;
    const int vv = v0 + 4 * r4;
    float4 bias;
    if (vv + 4 <= V_) bias = *(const float4*)(bp + vv);
    else {
        bias.x = (vv + 0 < V_) ? bp[vv + 0] : 0.f;
        bias.y = (vv + 1 < V_) ? bp[vv + 1] : 0.f;
        bias.z = (vv + 2 < V_) ? bp[vv + 2] : 0.f;
        bias.w = (vv + 3 < V_) ? bp[vv + 3] : 0.f;
    }
    float4 s[2];
    #pragma unroll
    for (int i = 0; i < 2; ++i) {
        const int b = 2 * bpair + i;
        float4 a = make_float4(bias.x, bias.y, bias.z, bias.w);
        #pragma unroll
        for (int c = 0; c < 4; ++c) {
            const float4 u = *(const float4*)&red[c][b][4 * r4];
            a.x += u.x; a.y += u.y; a.z += u.z; a.w += u.w;
        }
        s[i] = a;
    }
    __syncthreads();                          // red fully consumed
    #pragma unroll
    for (int i = 0; i < 2; ++i) {
        const int b = 2 * bpair + i;
        *(float4*)&lg[b * 64 + 4 * r4] = s[i];  // LDS: aligned, conflict-free
    }
    __syncthreads();

    // Store phase: wave w covers l = w, w+4, ...; lane = one v column.
    // Each store instr: 64 consecutive dwords = 256B contiguous.
    const int w    = t >> 6;
    const bool ok  = (v0 + vl) < V_;
    if (ok) {
        for (int b = 0; b < B_; ++b) {
            const float val = lg[b * 64 + vl];
            float* base = out + (size_t)b * OUTROW + v0 + vl;
            for (int l = w; l < LM1; l += 4) {
                __builtin_nontemporal_store(val, base + (size_t)l * V_);
            }
        }
    }
}

// ---------------------------------------------------------------------------
extern "C" void kernel_launch(void* const* d_in, const int* in_sizes, int n_in,
                              void* d_out, int out_size, void* d_ws, size_t ws_size,
                              hipStream_t stream) {
    (void)in_sizes; (void)n_in; (void)out_size;

    const int*   ids    = (const int*)  d_in[0];
    const float* hidden = (const float*)d_in[1];
    const float* emb    = (const float*)d_in[2];
    const float* Wb     = (const float*)d_in[3];
    const float* bb     = (const float*)d_in[4];
    const float* W_ih   = (const float*)d_in[5];
    const float* b_ih   = (const float*)d_in[6];
    const float* W_hh   = (const float*)d_in[7];
    const float* b_hh   = (const float*)d_in[8];
    const float* Wp     = (const float*)d_in[9];
    const float* bp     = (const float*)d_in[10];

    float* out = (float*)d_out;
    float* ws  = (float*)d_ws;

    // ws layout (floats): x0[16384] h0[16384] gx[49152] gh[49152] h1[16384]
    const size_t need_bytes = (size_t)(16384 * 2 + 49152 * 2 + 16384) * 4;
    float* h1;
    if (ws_size >= need_bytes) {
        float* x0b = ws;
        float* h0b = ws + 16384;
        float* gx  = ws + 32768;
        float* gh  = ws + 81920;
        h1         = ws + 131072;
        x0h0_kernel<<<B_, D_, 0, stream>>>(ids, hidden, emb, Wb, bb, x0b, h0b);
        gates_kernel<<<48, 256, 0, stream>>>(x0b, h0b, W_ih, W_hh, gx, gh);
        combine_kernel<<<64, 256, 0, stream>>>(gx, gh, b_ih, b_hh, h0b, h1);
    } else {
        h1 = ws;  // 64 KB fallback
        prep_kernel<<<B_, D_, 0, stream>>>(ids, hidden, emb, Wb, bb,
                                           W_ih, b_ih, W_hh, b_hh, h1);
    }

    logits_bcast_kernel<<<(V_ + 63) / 64, 256, 0, stream>>>(h1, Wp, bp, out);
}